// Round 7
// baseline (166.379 us; speedup 1.0000x reference)
//
#include <hip/hip_runtime.h>

// Problem constants (from reference setup_inputs): B=8, H=512, W=512
constexpr int B_ = 8;
constexpr int H_ = 512;
constexpr int W_ = 512;
constexpr int HW_ = H_ * W_;

constexpr int TS = 32;          // output tile = 32x32 pixels per block
constexpr int R_ = 4;           // halo radius = 2.83 sigma of flow (sigma=1.41)
constexpr int RS = 40;          // staged window = 40x40 pixels (always in-bounds)
constexpr int ROWB = RS * 12;   // 480 B per image row segment (fp32 RGB)
constexpr int PAIRB = 2 * ROWB; // 960 B: [img0 row | img1 row]

// v7: staging via global_load_lds DMA (fire-and-forget, no VGPR round-trip).
// Window origin clamped to [0, W-RS] so the staged rect is ALWAYS fully
// in-bounds -> each row is a contiguous, 16B-aligned 480 B global segment.
// One DMA instr per row stages BOTH images: lanes 0-29 -> img0, 30-59 -> img1.
// LDS holds raw fp32 (exact arithmetic; fp16 quantization gone).
// Theory: all prior variants pinned at ~50us with every pipe idle because
// register-staged loads expose only ~2-4 outstanding loads/wave; DMA exposes
// 10x 1KB per wave with zero register pressure.

// Bilinear sample from the fp32 LDS window; clamped coords outside the
// window (|flow|>R tail, ~1%/sample) fall back to exact global gather.
template <int IMG>
__device__ __forceinline__ void sampleT(const char* __restrict__ lds,
                                        const float* __restrict__ img,
                                        int gx0, int gy0,
                                        float sx, float sy, float g[3]) {
    float xf = floorf(sx), yf = floorf(sy);
    float wx = sx - xf, wy = sy - yf;
    int ix = (int)xf, iy = (int)yf;
    int x0 = min(max(ix, 0), W_ - 1);
    int x1 = min(max(ix + 1, 0), W_ - 1);
    int y0 = min(max(iy, 0), H_ - 1);
    int y1 = min(max(iy + 1, 0), H_ - 1);

    float w00 = (1.0f - wx) * (1.0f - wy);
    float w01 = wx * (1.0f - wy);
    float w10 = (1.0f - wx) * wy;
    float w11 = wx * wy;

    int lx0 = x0 - gx0, lx1 = x1 - gx0;
    int ly0 = y0 - gy0, ly1 = y1 - gy0;
    bool inT = ((unsigned)lx0 < (unsigned)RS) & ((unsigned)lx1 < (unsigned)RS) &
               ((unsigned)ly0 < (unsigned)RS) & ((unsigned)ly1 < (unsigned)RS);

    if (inT) {
        const float* t00 = (const float*)(lds + ly0 * PAIRB + IMG * ROWB + lx0 * 12);
        const float* t01 = (const float*)(lds + ly0 * PAIRB + IMG * ROWB + lx1 * 12);
        const float* t10 = (const float*)(lds + ly1 * PAIRB + IMG * ROWB + lx0 * 12);
        const float* t11 = (const float*)(lds + ly1 * PAIRB + IMG * ROWB + lx1 * 12);
        #pragma unroll
        for (int ch = 0; ch < 3; ++ch)
            g[ch] = t00[ch] * w00 + t01[ch] * w01 +
                    t10[ch] * w10 + t11[ch] * w11;
    } else {
        const float* pa = img + ((size_t)y0 * W_ + x0) * 3;
        const float* pb = img + ((size_t)y0 * W_ + x1) * 3;
        const float* pc = img + ((size_t)y1 * W_ + x0) * 3;
        const float* pd = img + ((size_t)y1 * W_ + x1) * 3;
        #pragma unroll
        for (int ch = 0; ch < 3; ++ch)
            g[ch] = pa[ch] * w00 + pb[ch] * w01 +
                    pc[ch] * w10 + pd[ch] * w11;
    }
}

__global__ __launch_bounds__(256, 4) void frame_interp_dma(
    const float* __restrict__ t,       // (B)
    const float* __restrict__ I0,      // (B,H,W,3)
    const float* __restrict__ I1,      // (B,H,W,3)
    const float* __restrict__ interp,  // (B,H,W,5)
    const float* __restrict__ F0,      // (B,H,W,2)
    const float* __restrict__ F1,      // (B,H,W,2)
    float* __restrict__ out)           // (B,H,W,3)
{
    // Raw fp32 window: 40 row-pairs x 960 B = 38400 B -> 4 blocks/CU.
    __shared__ __align__(16) char lds_raw[RS * PAIRB];

    int tid  = threadIdx.x;
    int lane = tid & 63;
    int wave = tid >> 6;
    int bid  = blockIdx.x;
    // XCD swizzle: bid%8 = batch -> each XCD's L2 holds one batch's images.
    int b    = bid & 7;
    int tile = bid >> 3;       // 0..255
    int ty   = tile >> 4;      // 0..15
    int tx   = tile & 15;      // 0..15
    // In-bounds window origin (multiple of 4 in x -> 16B-aligned rows).
    int gx0 = min(max(tx * TS - R_, 0), W_ - RS);
    int gy0 = min(max(ty * TS - R_, 0), H_ - RS);

    const float* img0 = I0 + (size_t)b * HW_ * 3;
    const float* img1 = I1 + (size_t)b * HW_ * 3;

    float tb = t[b];

    // ---- DMA-stage the 40x40 fp32 window of both images ----
    // Row r: lanes 0-29 copy img0[gy0+r][gx0..gx0+39] (480 B as 30x16 B),
    //        lanes 30-59 copy the same row of img1. Dest = base + lane*16.
    #pragma unroll
    for (int j = 0; j < 10; ++j) {
        int r  = wave * 10 + j;
        int gy = gy0 + r;
        char* ldsbase = lds_raw + r * PAIRB;       // wave-uniform
        const char* g0row = (const char*)(img0 + ((size_t)gy * W_ + gx0) * 3);
        const char* g1row = (const char*)(img1 + ((size_t)gy * W_ + gx0) * 3);
        if (lane < 60) {
            const char* src = (lane < 30) ? g0row + lane * 16
                                          : g1row + (lane - 30) * 16;
            __builtin_amdgcn_global_load_lds(
                (const __attribute__((address_space(1))) void*)src,
                (__attribute__((address_space(3))) void*)ldsbase,
                16, 0, 0);
        }
    }

    // ---- Per-thread streams: 4 CONTIGUOUS pixels -> pure dwordx4 ----
    int row  = tid >> 3;              // 0..31
    int colb = (tid & 7) * 4;         // 0,4,...,28
    int gy_o = ty * TS + row;
    int gx_o = tx * TS + colb;
    size_t idx0 = (size_t)b * HW_ + (size_t)gy_o * W_ + gx_o;  // multiple of 4

    float ii[20], f0v[8], f1v[8];
    __builtin_memcpy(ii, interp + idx0 * 5, 80);   // 5x dwordx4
    __builtin_memcpy(f0v, F0 + idx0 * 2, 32);      // 2x dwordx4
    __builtin_memcpy(f1v, F1 + idx0 * 2, 32);      // 2x dwordx4

    // Drain DMA + stream loads, then block barrier.
    asm volatile("s_waitcnt vmcnt(0)" ::: "memory");
    __syncthreads();

    // ---- Compute 4 contiguous pixels ----
    float o[12];
    #pragma unroll
    for (int k = 0; k < 4; ++k) {
        float fx = (float)(gx_o + k);
        float fy = (float)gy_o;
        float sx0 = fx + ii[k * 5 + 0] + f0v[k * 2 + 0];
        float sy0 = fy + ii[k * 5 + 1] + f0v[k * 2 + 1];
        float sx1 = fx + ii[k * 5 + 2] + f1v[k * 2 + 0];
        float sy1 = fy + ii[k * 5 + 3] + f1v[k * 2 + 1];
        float vt0 = 1.0f / (1.0f + __expf(-ii[k * 5 + 4]));

        float g0[3], g1[3];
        sampleT<0>(lds_raw, img0, gx0, gy0, sx0, sy0, g0);
        sampleT<1>(lds_raw, img1, gx0, gy0, sx1, sy1, g1);

        float w0 = (1.0f - tb) * vt0;
        float w1 = tb * (1.0f - vt0);
        float inv = 1.0f / (w0 + w1 + 1e-12f);
        o[k * 3 + 0] = (w0 * g0[0] + w1 * g1[0]) * inv;
        o[k * 3 + 1] = (w0 * g0[1] + w1 * g1[1]) * inv;
        o[k * 3 + 2] = (w0 * g0[2] + w1 * g1[2]) * inv;
    }
    __builtin_memcpy(out + idx0 * 3, o, 48);       // 3x dwordx4
}

extern "C" void kernel_launch(void* const* d_in, const int* in_sizes, int n_in,
                              void* d_out, int out_size, void* d_ws, size_t ws_size,
                              hipStream_t stream) {
    const float* t      = (const float*)d_in[0];
    const float* I0     = (const float*)d_in[1];
    const float* I1     = (const float*)d_in[2];
    const float* interp = (const float*)d_in[3];
    const float* F0     = (const float*)d_in[4];
    const float* F1     = (const float*)d_in[5];
    float* out = (float*)d_out;

    int blocks = B_ * (H_ / TS) * (W_ / TS);  // 2048
    frame_interp_dma<<<blocks, 256, 0, stream>>>(t, I0, I1, interp, F0, F1, out);
}

// Round 8
// 165.510 us; speedup vs baseline: 1.0053x; 1.0053x over previous
//
#include <hip/hip_runtime.h>

// Problem constants (from reference setup_inputs): B=8, H=512, W=512
constexpr int B_ = 8;
constexpr int H_ = 512;
constexpr int W_ = 512;
constexpr int HW_ = H_ * W_;

constexpr int TS = 32;           // output tile = 32x32
constexpr int R_ = 4;            // halo radius (2.83 sigma of flow)
constexpr int RS = 40;           // staged window 40x40, always in-bounds
constexpr int ROWB = RS * 12;    // 480 B per image row (fp32 RGB)
constexpr int PAIRB = 2 * ROWB;  // 960 B: [img0 row | img1 row]
constexpr int TILEB = RS * PAIRB;// 38400 B per tile window

// v8: BREAK PHASE LOCKSTEP. All prior variants (50-60us, all pipes <20%)
// ran stage -> full-drain barrier -> compute in lockstep across every wave
// on the CU, so memory and compute phases serialized chip-wide.
// Here each block pipelines TWO tiles: DMA-stage A and B back-to-back,
// counted s_waitcnt vmcnt(10) (only A's DMAs drained) + RAW s_barrier,
// compute A while B's DMA is still in flight, then vmcnt(0) + barrier,
// compute B. __syncthreads is NOT used (it emits vmcnt(0) drain).
// OOB taps: clamped-LDS fast path + exact per-pixel global fixup.

__device__ __forceinline__ void sampleG(const float* __restrict__ img,
                                        float sx, float sy, float g[3]) {
    float xf = floorf(sx), yf = floorf(sy);
    float wx = sx - xf, wy = sy - yf;
    int ix = (int)xf, iy = (int)yf;
    int x0 = min(max(ix, 0), W_ - 1);
    int x1 = min(max(ix + 1, 0), W_ - 1);
    int y0 = min(max(iy, 0), H_ - 1);
    int y1 = min(max(iy + 1, 0), H_ - 1);
    float w00 = (1.0f - wx) * (1.0f - wy);
    float w01 = wx * (1.0f - wy);
    float w10 = (1.0f - wx) * wy;
    float w11 = wx * wy;
    float a[3], bv[3], c[3], d[3];
    __builtin_memcpy(a,  img + ((size_t)y0 * W_ + x0) * 3, 12);
    __builtin_memcpy(bv, img + ((size_t)y0 * W_ + x1) * 3, 12);
    __builtin_memcpy(c,  img + ((size_t)y1 * W_ + x0) * 3, 12);
    __builtin_memcpy(d,  img + ((size_t)y1 * W_ + x1) * 3, 12);
    #pragma unroll
    for (int ch = 0; ch < 3; ++ch)
        g[ch] = a[ch] * w00 + bv[ch] * w01 + c[ch] * w10 + d[ch] * w11;
}

// Fast path: fp32 taps from the LDS window with indices clamped into the
// window (safe garbage when out-of-window); returns whether result is valid.
template <int IMG>
__device__ __forceinline__ bool sampleL(const char* lds, int gx0, int gy0,
                                        float sx, float sy, float g[3]) {
    float xf = floorf(sx), yf = floorf(sy);
    float wx = sx - xf, wy = sy - yf;
    int ix = (int)xf, iy = (int)yf;
    int x0 = min(max(ix, 0), W_ - 1);
    int x1 = min(max(ix + 1, 0), W_ - 1);
    int y0 = min(max(iy, 0), H_ - 1);
    int y1 = min(max(iy + 1, 0), H_ - 1);
    float w00 = (1.0f - wx) * (1.0f - wy);
    float w01 = wx * (1.0f - wy);
    float w10 = (1.0f - wx) * wy;
    float w11 = wx * wy;

    int lx0 = x0 - gx0, lx1 = x1 - gx0;
    int ly0 = y0 - gy0, ly1 = y1 - gy0;
    bool ok = ((unsigned)lx0 < (unsigned)RS) & ((unsigned)lx1 < (unsigned)RS) &
              ((unsigned)ly0 < (unsigned)RS) & ((unsigned)ly1 < (unsigned)RS);
    // clamp into window for a safe (possibly wrong) read; fixup handles !ok
    lx0 = min(max(lx0, 0), RS - 1);
    lx1 = min(max(lx1, 0), RS - 1);
    ly0 = min(max(ly0, 0), RS - 1);
    ly1 = min(max(ly1, 0), RS - 1);

    const float* t00 = (const float*)(lds + ly0 * PAIRB + IMG * ROWB + lx0 * 12);
    const float* t01 = (const float*)(lds + ly0 * PAIRB + IMG * ROWB + lx1 * 12);
    const float* t10 = (const float*)(lds + ly1 * PAIRB + IMG * ROWB + lx0 * 12);
    const float* t11 = (const float*)(lds + ly1 * PAIRB + IMG * ROWB + lx1 * 12);
    #pragma unroll
    for (int ch = 0; ch < 3; ++ch)
        g[ch] = t00[ch] * w00 + t01[ch] * w01 + t10[ch] * w10 + t11[ch] * w11;
    return ok;
}

__device__ __forceinline__ void computeTile(
    const char* lds, int gx0, int gy0, int gx_o, int gy_o,
    const float* __restrict__ img0, const float* __restrict__ img1, float tb,
    const float ii[20], const float f0v[8], const float f1v[8], float o[12])
{
    #pragma unroll
    for (int k = 0; k < 4; ++k) {
        float fx = (float)(gx_o + k);
        float fy = (float)gy_o;
        float sx0 = fx + ii[k * 5 + 0] + f0v[k * 2 + 0];
        float sy0 = fy + ii[k * 5 + 1] + f0v[k * 2 + 1];
        float sx1 = fx + ii[k * 5 + 2] + f1v[k * 2 + 0];
        float sy1 = fy + ii[k * 5 + 3] + f1v[k * 2 + 1];
        float vt0 = 1.0f / (1.0f + __expf(-ii[k * 5 + 4]));

        float g0[3], g1[3];
        bool ok0 = sampleL<0>(lds, gx0, gy0, sx0, sy0, g0);
        bool ok1 = sampleL<1>(lds, gx0, gy0, sx1, sy1, g1);
        if (!ok0) sampleG(img0, sx0, sy0, g0);   // rare exact fixup
        if (!ok1) sampleG(img1, sx1, sy1, g1);

        float w0 = (1.0f - tb) * vt0;
        float w1 = tb * (1.0f - vt0);
        float inv = 1.0f / (w0 + w1 + 1e-12f);
        o[k * 3 + 0] = (w0 * g0[0] + w1 * g1[0]) * inv;
        o[k * 3 + 1] = (w0 * g0[1] + w1 * g1[1]) * inv;
        o[k * 3 + 2] = (w0 * g0[2] + w1 * g1[2]) * inv;
    }
}

// Stage the 40x40 fp32 window of both images for one tile via DMA.
// Row r: lanes 0-29 copy img0 row (480 B as 30x16 B), lanes 30-59 img1.
__device__ __forceinline__ void stageTile(char* lds,
                                          const float* __restrict__ img0,
                                          const float* __restrict__ img1,
                                          int gx0, int gy0, int wave, int lane)
{
    #pragma unroll
    for (int j = 0; j < 10; ++j) {
        int r  = wave * 10 + j;
        int gy = gy0 + r;
        char* ldsbase = lds + r * PAIRB;   // wave-uniform dest base
        const char* g0row = (const char*)(img0 + ((size_t)gy * W_ + gx0) * 3);
        const char* g1row = (const char*)(img1 + ((size_t)gy * W_ + gx0) * 3);
        if (lane < 60) {
            const char* src = (lane < 30) ? g0row + lane * 16
                                          : g1row + (lane - 30) * 16;
            __builtin_amdgcn_global_load_lds(
                (const __attribute__((address_space(1))) void*)src,
                (__attribute__((address_space(3))) void*)ldsbase,
                16, 0, 0);
        }
    }
}

__global__ __launch_bounds__(256, 2) void frame_interp_pipe(
    const float* __restrict__ t,       // (B)
    const float* __restrict__ I0,      // (B,H,W,3)
    const float* __restrict__ I1,      // (B,H,W,3)
    const float* __restrict__ interp,  // (B,H,W,5)
    const float* __restrict__ F0,      // (B,H,W,2)
    const float* __restrict__ F1,      // (B,H,W,2)
    float* __restrict__ out)           // (B,H,W,3)
{
    __shared__ __align__(16) char lds[2][TILEB];   // 76.8 KB -> 2 blocks/CU

    int tid  = threadIdx.x;
    int lane = tid & 63;
    int wave = tid >> 6;
    int bid  = blockIdx.x;                // 1024 blocks
    // XCD swizzle: bid%8 = batch -> each XCD's L2 holds one batch's images.
    int b   = bid & 7;
    int sup = bid >> 3;                   // 0..127
    int ty  = sup >> 3;                   // 0..15
    int px  = sup & 7;                    // tile-pair column 0..7
    int txA = px * 2, txB = px * 2 + 1;

    int gy0  = min(max(ty  * TS - R_, 0), H_ - RS);
    int gx0A = min(max(txA * TS - R_, 0), W_ - RS);   // multiple of 4
    int gx0B = min(max(txB * TS - R_, 0), W_ - RS);

    const float* img0 = I0 + (size_t)b * HW_ * 3;
    const float* img1 = I1 + (size_t)b * HW_ * 3;
    float tb = t[b];

    // ---- Per-thread streams (oldest VMEM ops; drained by the counted wait) ----
    int row  = tid >> 3;               // 0..31
    int colb = (tid & 7) * 4;          // 0,4,...,28
    int gy_o  = ty * TS + row;
    int gx_oA = txA * TS + colb;
    size_t idxA = (size_t)b * HW_ + (size_t)gy_o * W_ + gx_oA;  // mult of 4
    size_t idxB = idxA + TS;           // tile B = +32 columns, same row

    float iiA[20], f0A[8], f1A[8], iiB[20], f0B[8], f1B[8];
    __builtin_memcpy(iiA, interp + idxA * 5, 80);
    __builtin_memcpy(f0A, F0 + idxA * 2, 32);
    __builtin_memcpy(f1A, F1 + idxA * 2, 32);
    __builtin_memcpy(iiB, interp + idxB * 5, 80);
    __builtin_memcpy(f0B, F0 + idxB * 2, 32);
    __builtin_memcpy(f1B, F1 + idxB * 2, 32);

    // ---- DMA both tiles back-to-back (exactly 10+10 vmcnt ops per wave) ----
    stageTile(lds[0], img0, img1, gx0A, gy0, wave, lane);
    stageTile(lds[1], img0, img1, gx0B, gy0, wave, lane);

    // Wait: everything older than tile-B DMA (streams + tile-A DMA) done;
    // tile-B's 10 DMAs stay in flight across the barrier.
    asm volatile("s_waitcnt vmcnt(10)" ::: "memory");
    __builtin_amdgcn_sched_barrier(0);
    __builtin_amdgcn_s_barrier();      // raw barrier: no vmcnt(0) drain

    float oA[12];
    computeTile(lds[0], gx0A, gy0, gx_oA, gy_o, img0, img1, tb,
                iiA, f0A, f1A, oA);

    // Tile-B DMA (and any fixup loads) drained; then block barrier.
    asm volatile("s_waitcnt vmcnt(0)" ::: "memory");
    __builtin_amdgcn_sched_barrier(0);
    __builtin_amdgcn_s_barrier();

    float oB[12];
    computeTile(lds[1], gx0B, gy0, gx_oA + TS, gy_o, img0, img1, tb,
                iiB, f0B, f1B, oB);

    __builtin_memcpy(out + idxA * 3, oA, 48);   // 3x dwordx4
    __builtin_memcpy(out + idxB * 3, oB, 48);
}

extern "C" void kernel_launch(void* const* d_in, const int* in_sizes, int n_in,
                              void* d_out, int out_size, void* d_ws, size_t ws_size,
                              hipStream_t stream) {
    const float* t      = (const float*)d_in[0];
    const float* I0     = (const float*)d_in[1];
    const float* I1     = (const float*)d_in[2];
    const float* interp = (const float*)d_in[3];
    const float* F0     = (const float*)d_in[4];
    const float* F1     = (const float*)d_in[5];
    float* out = (float*)d_out;

    int blocks = B_ * (H_ / TS) * (W_ / (2 * TS));  // 8*16*8 = 1024
    frame_interp_pipe<<<blocks, 256, 0, stream>>>(t, I0, I1, interp, F0, F1, out);
}